// Round 1
// baseline (3238.320 us; speedup 1.0000x reference)
//
#include <hip/hip_runtime.h>
#include <hip/hip_bf16.h>

// Elman RNN: B=128, T=256, I=512, H=1024
//   xp = x @ W_ih^T + b_ih          (one big GEMM, bf16 MFMA)
//   h_t = tanh(xp_t + h_{t-1} @ W_hh^T + b_hh)   (256 sequential step kernels)
// Precision: bf16 inputs, fp32 MFMA accumulate, fp32 tanh, fp32 output.

#define B_SZ 128
#define T_SZ 256
#define I_SZ 512
#define H_SZ 1024

typedef __bf16 bf16x8 __attribute__((ext_vector_type(8)));
typedef __bf16 bf16x4 __attribute__((ext_vector_type(4)));
typedef float f32x4 __attribute__((ext_vector_type(4)));

// ---------------- fp32 -> bf16 convert (vectorized x4) ----------------
__global__ void cvt_kernel(const float* __restrict__ src, __bf16* __restrict__ dst, int n4) {
    int i = blockIdx.x * blockDim.x + threadIdx.x;
    if (i < n4) {
        float4 v = reinterpret_cast<const float4*>(src)[i];
        bf16x4 o;
        o[0] = (__bf16)v.x; o[1] = (__bf16)v.y; o[2] = (__bf16)v.z; o[3] = (__bf16)v.w;
        reinterpret_cast<bf16x4*>(dst)[i] = o;
    }
}

// ---------------- input projection: xp[bt,h] = x[bt,:] . W_ih[h,:] + b_ih[h] ----------------
// grid: (BT/16, H/64), block 256 (4 waves, each wave one 16x16 n-subtile)
__global__ __launch_bounds__(256) void proj_kernel(const __bf16* __restrict__ x,
                                                   const __bf16* __restrict__ wih,
                                                   const float* __restrict__ bih,
                                                   __bf16* __restrict__ xp) {
    const int m0   = blockIdx.x * 16;
    const int n0   = blockIdx.y * 64;
    const int lane = threadIdx.x & 63;
    const int wave = threadIdx.x >> 6;
    const int lm   = lane & 15;   // A-row / B-row (n) within tile
    const int quad = lane >> 4;   // k-chunk selector
    const int nw   = n0 + wave * 16;

    f32x4 acc = {0.f, 0.f, 0.f, 0.f};
    const __bf16* arow = x   + (size_t)(m0 + lm) * I_SZ + quad * 8;
    const __bf16* brow = wih + (size_t)(nw + lm) * I_SZ + quad * 8;
#pragma unroll 4
    for (int k = 0; k < I_SZ; k += 32) {
        bf16x8 a = *reinterpret_cast<const bf16x8*>(arow + k);
        bf16x8 b = *reinterpret_cast<const bf16x8*>(brow + k);
        acc = __builtin_amdgcn_mfma_f32_16x16x32_bf16(a, b, acc, 0, 0, 0);
    }
    const int col  = nw + lm;
    const float bias = bih[col];
#pragma unroll
    for (int r = 0; r < 4; ++r) {
        int row = m0 + quad * 4 + r;
        xp[(size_t)row * H_SZ + col] = (__bf16)(acc[r] + bias);
    }
}

// ---------------- one recurrent step ----------------
// u[b,n] = sum_k hprev[b,k]*W_hh[n,k] ; h = tanh(u + xp[b,t,n] + b_hh[n])
// grid: (B/16, H/64), block 256
__global__ __launch_bounds__(256) void step_kernel(const __bf16* __restrict__ hprev,
                                                   const __bf16* __restrict__ whh,
                                                   const __bf16* __restrict__ xp,
                                                   const float* __restrict__ bhh,
                                                   float* __restrict__ out_states,
                                                   __bf16* __restrict__ hnext,
                                                   float* __restrict__ hlast,
                                                   int t, int is_last) {
    const int m0   = blockIdx.x * 16;
    const int n0   = blockIdx.y * 64;
    const int lane = threadIdx.x & 63;
    const int wave = threadIdx.x >> 6;
    const int lm   = lane & 15;
    const int quad = lane >> 4;
    const int nw   = n0 + wave * 16;

    f32x4 acc = {0.f, 0.f, 0.f, 0.f};
    const __bf16* arow = hprev + (size_t)(m0 + lm) * H_SZ + quad * 8;
    const __bf16* brow = whh   + (size_t)(nw + lm) * H_SZ + quad * 8;
#pragma unroll 4
    for (int k = 0; k < H_SZ; k += 32) {
        bf16x8 a = *reinterpret_cast<const bf16x8*>(arow + k);
        bf16x8 b = *reinterpret_cast<const bf16x8*>(brow + k);
        acc = __builtin_amdgcn_mfma_f32_16x16x32_bf16(a, b, acc, 0, 0, 0);
    }
    const int col = nw + lm;
    const float bias = bhh[col];
#pragma unroll
    for (int r = 0; r < 4; ++r) {
        int row = m0 + quad * 4 + r;                       // batch index
        size_t bt = (size_t)row * T_SZ + t;
        float u = acc[r] + (float)xp[bt * H_SZ + col] + bias;
        float h = tanhf(u);
        out_states[bt * H_SZ + col] = h;
        hnext[(size_t)row * H_SZ + col] = (__bf16)h;
        if (is_last) hlast[(size_t)row * H_SZ + col] = h;
    }
}

extern "C" void kernel_launch(void* const* d_in, const int* in_sizes, int n_in,
                              void* d_out, int out_size, void* d_ws, size_t ws_size,
                              hipStream_t stream) {
    const float* x    = (const float*)d_in[0];   // [B,T,I]
    const float* Wih  = (const float*)d_in[1];   // [H,I]
    const float* Whh  = (const float*)d_in[2];   // [H,H]
    const float* bih  = (const float*)d_in[3];   // [H]
    const float* bhh  = (const float*)d_in[4];   // [H]

    float* states = (float*)d_out;                               // [B,T,H]
    float* hlast  = (float*)d_out + (size_t)B_SZ * T_SZ * H_SZ;  // [B,H]

    // workspace carve (bytes), all 16B aligned
    char* w = (char*)d_ws;
    __bf16* x_bf   = (__bf16*)w;  w += (size_t)B_SZ * T_SZ * I_SZ * 2;  // 33.5 MB
    __bf16* wih_bf = (__bf16*)w;  w += (size_t)H_SZ * I_SZ * 2;         // 1 MB
    __bf16* whh_bf = (__bf16*)w;  w += (size_t)H_SZ * H_SZ * 2;         // 2 MB
    __bf16* xp_bf  = (__bf16*)w;  w += (size_t)B_SZ * T_SZ * H_SZ * 2;  // 67 MB
    __bf16* hA     = (__bf16*)w;  w += (size_t)B_SZ * H_SZ * 2;         // 256 KB
    __bf16* hB     = (__bf16*)w;  w += (size_t)B_SZ * H_SZ * 2;         // 256 KB
    (void)ws_size;

    // converts
    {
        int n4 = B_SZ * T_SZ * I_SZ / 4;   // 4,194,304
        cvt_kernel<<<(n4 + 255) / 256, 256, 0, stream>>>(x, x_bf, n4);
    }
    {
        int n4 = H_SZ * I_SZ / 4;          // 131,072
        cvt_kernel<<<(n4 + 255) / 256, 256, 0, stream>>>(Wih, wih_bf, n4);
    }
    {
        int n4 = H_SZ * H_SZ / 4;          // 262,144
        cvt_kernel<<<(n4 + 255) / 256, 256, 0, stream>>>(Whh, whh_bf, n4);
    }

    // h0 = 0
    hipMemsetAsync(hA, 0, (size_t)B_SZ * H_SZ * 2, stream);

    // input projection
    {
        dim3 grid(B_SZ * T_SZ / 16, H_SZ / 64);  // (2048, 16)
        proj_kernel<<<grid, 256, 0, stream>>>(x_bf, wih_bf, bih, xp_bf);
    }

    // sequential recurrence: 256 step kernels (graph-captured)
    {
        dim3 grid(B_SZ / 16, H_SZ / 64);  // (8, 16)
        for (int t = 0; t < T_SZ; ++t) {
            const __bf16* hp = (t & 1) ? hB : hA;
            __bf16*       hn = (t & 1) ? hA : hB;
            step_kernel<<<grid, 256, 0, stream>>>(hp, whh_bf, xp_bf, bhh,
                                                  states, hn, hlast,
                                                  t, (t == T_SZ - 1) ? 1 : 0);
        }
    }
}